// Round 7
// baseline (221.733 us; speedup 1.0000x reference)
//
#include <hip/hip_runtime.h>

// KNN argmin over L2, round 26: TWO dispatches (prep eliminated).
//
// The ~48.5us per-dispatch floor: across R19-R25 (four structurally
// different kernel sets) NO dispatch ever measured < 48.5us, and every
// total = sum of max(real_work, ~48.5): R19 55.8+49+49=154; R24
// 50+49+49=153; R25 3x48.6=145.8 EXACTLY. Honest work accounting: prep
// ~5-8, phaseA(R25) ~10-20, phaseB ~30-40 (1GB L2 rescore ~29us floor).
// => dominant term is a fixed per-dispatch cost; only dispatch-count
// reduction moves it. R23's fusion failure was register spills (38MB
// scratch), not evidence against the floor.
//
// K1 (phaseA, self-contained): builds Q fragments from raw f32 Q (RNE cvt
// == old prep, bitwise-identical fragments); stages raw f32 S rows per
// 64-support chunk via global_load_lds with PRE-SWIZZLED global source
// (db ^= r&7 -> balanced LDS bank quads on fragment reads, rule-21:
// both-sides-or-neither); f16 cvt at read time; |s|^2 derived from the
// staged registers (16 fmaf + butterfly + shfl gather) for cinit and a
// one-time sqS write (blockIdx.y==0). Emits bmin as before.
// K2 (phaseB): R21 body, but reads S ROWS directly (same bytes, same
// d-ascending fp32 chains -> identical keys; S_T dead) and computes sqQ
// locally from sQrow. onehot/out path unchanged.
//
// Certificate unchanged: c = 2^-9*1.01 <= 0.002, eps = 0.004|q|^2 + 0.05;
// bmin encodes 0.998|s|^2 - 2 cross_f16 via cinit = -0.499|s|^2. Only
// numeric delta vs R25: |s|^2 summation order (tree vs serial), bounded
// ~2.5e-4, absorbed by the 0.05 slack budgeted for accumulation rounding.
//
// Ledger: R19 153.3 | R20 steal 153.0 | R21 reg-staging 145.8 | R22 fence
// no-op 148.3 | R23 coop fusion 314.8 (spills) | R24 128q phaseA 153.1 |
// R25 LDS phaseA 145.8 (=3x48.6). Prediction: floor right -> ~97-105us;
// wrong -> ~85-100 with both kernels finally visible in top-5.

#define NTOT   16384
#define DIM    64
#define EPS_COEF 0.004f   // 2c with c=0.002 (>= 2^-9*1.01)
#define EPS_ABS  0.05f
#define CINIT_COEF (-0.499f)  // -(1-c)/2
#define FLT_BIG 3.4e38f

typedef __attribute__((ext_vector_type(8))) short short8;
typedef __attribute__((ext_vector_type(4))) float float4v;

__device__ __forceinline__ ushort f16_bits(float x) {
  union { _Float16 f; ushort u; } c;
  c.f = (_Float16)x;  // v_cvt_f16_f32, RNE
  return c.u;
}

// Opaque def: forbids rematerialization (forces register residency).
__device__ __forceinline__ void pin8(short8& v) {
  asm volatile("" : "+v"(v));
}

#define MFMA16F(A, B, C) __builtin_amdgcn_mfma_f32_16x16x32_f16(A, B, C, 0, 0, 0)

// ---------------------------------------------------------------------------
// K1: block = 256 queries x 512 supports; grid (32 splits, 64 q-tiles).
// Per chunk of 64 supports: stage 16KB f32 rows (swizzled), fragments +
// |s|^2 from registers, 8 MFMA per step, v_max3 fold, bmin = -2*max.
// split -> XCD via linear%8 = blockIdx.x%8 (32y%8==0): slice stays local.
template <int BST>  // 16-support steps per bmin block: 8 -> SBLK=128
__global__ __launch_bounds__(256, 4) void k_phaseA(
    const float* __restrict__ S, const float* __restrict__ Q,
    float* __restrict__ sqS, float* __restrict__ bmin) {
  constexpr int NSB = NTOT / (16 * BST);   // 128 or 64
  constexpr int SBLK = 16 * BST;
  __shared__ float schunk[2][4096];        // 2 x 16KB, rows swizzled

  const int tid = threadIdx.x;
  const int l = tid & 63;
  const int w = tid >> 6;
  const int lm = l & 15;
  const int lq = l >> 4;
  const int split = blockIdx.x;            // 0..31
  const int qbase = blockIdx.y * 256 + w * 64;
  const int sbase = split * 512;
  const bool writeSq = (blockIdx.y == 0);

  // Q (B) fragments straight from f32 Q. Element j of qh[t][h] =
  // f16(Q[qbase+t*16+(l&15)][h*32+(l>>4)*8+j]) -- identical to the old
  // prep panel + load path (same RNE cvt => bitwise-equal fragments).
  short8 qh[4][2];
#pragma unroll
  for (int t = 0; t < 4; ++t) {
    const float* qp = Q + (size_t)(qbase + t * 16 + lm) * 64 + lq * 8;
#pragma unroll
    for (int h = 0; h < 2; ++h) {
      const float4 a = *(const float4*)(qp + h * 32);
      const float4 b = *(const float4*)(qp + h * 32 + 4);
      short8 v;
      v[0] = (short)f16_bits(a.x); v[1] = (short)f16_bits(a.y);
      v[2] = (short)f16_bits(a.z); v[3] = (short)f16_bits(a.w);
      v[4] = (short)f16_bits(b.x); v[5] = (short)f16_bits(b.y);
      v[6] = (short)f16_bits(b.z); v[7] = (short)f16_bits(b.w);
      qh[t][h] = v;
    }
  }
#pragma unroll
  for (int t = 0; t < 4; ++t) { pin8(qh[t][0]); pin8(qh[t][1]); }

  // Swizzled stage: logical (row r, 16B-block db) stored at byte
  // r*256 + (db ^ (r&7))*16. global_load_lds dest is linear (base +
  // lane*16), so the swizzle is applied on the per-lane GLOBAL source
  // (rule 21: source permutation == read permutation).
  auto stage = [&](int c, int b) {
    const size_t cb = (size_t)(sbase + c * 64) * 64;  // chunk float offset
#pragma unroll
    for (int I = 0; I < 4; ++I) {
      const int r = w * 16 + I * 4 + (l >> 4);   // dest row for this lane
      const int dbl_ = lm ^ (r & 7);             // logical 16B block
      const float* gs = S + cb + (size_t)r * 64 + dbl_ * 4;
      float* ls = &schunk[b][w * 1024 + I * 256];
      __builtin_amdgcn_global_load_lds(
          (const __attribute__((address_space(1))) void*)(const void*)gs,
          (__attribute__((address_space(3))) void*)(void*)ls, 16, 0, 0);
    }
  };

  const int xb = (l & 7) << 4;                        // swizzle key (bytes)
  const int o0f = ((lq * 32) ^ xb) >> 2;              // h0 lo float offset
  const int o1f = (((lq * 32) + 16) ^ xb) >> 2;       // h0 hi float offset

  float bmr[4] = {-FLT_BIG, -FLT_BIG, -FLT_BIG, -FLT_BIG};

  stage(0, 0);
  __syncthreads();  // vmcnt(0) drain: chunk 0 resident

  for (int c = 0; c < 8; ++c) {
    const int b = c & 1;
    if (c + 1 < 8) stage(c + 1, b ^ 1);  // async issue before compute

#pragma unroll
    for (int st = 0; st < 4; ++st) {
      const float* sp = &schunk[b][(st * 16 + lm) * 64];
      const float4 x0a = *(const float4*)(sp + o0f);        // d: lq*8..+4
      const float4 x0b = *(const float4*)(sp + o1f);        // d: lq*8+4..+8
      const float4 x1a = *(const float4*)(sp + o0f + 32);   // d: 32+lq*8..
      const float4 x1b = *(const float4*)(sp + o1f + 32);

      // |s|^2 of row (st*16+lm) from staged regs: 16 partial dims per
      // lane, butterfly over the 4 lq-groups (tree order; certified by
      // the 0.05 slack), then gather per-cinit-slot via shfl.
      float p = 0.f;
      p = fmaf(x0a.x, x0a.x, p); p = fmaf(x0a.y, x0a.y, p);
      p = fmaf(x0a.z, x0a.z, p); p = fmaf(x0a.w, x0a.w, p);
      p = fmaf(x0b.x, x0b.x, p); p = fmaf(x0b.y, x0b.y, p);
      p = fmaf(x0b.z, x0b.z, p); p = fmaf(x0b.w, x0b.w, p);
      p = fmaf(x1a.x, x1a.x, p); p = fmaf(x1a.y, x1a.y, p);
      p = fmaf(x1a.z, x1a.z, p); p = fmaf(x1a.w, x1a.w, p);
      p = fmaf(x1b.x, x1b.x, p); p = fmaf(x1b.y, x1b.y, p);
      p = fmaf(x1b.z, x1b.z, p); p = fmaf(x1b.w, x1b.w, p);
      p += __shfl_xor(p, 16, 64);
      p += __shfl_xor(p, 32, 64);
      if (writeSq && lq == 0) sqS[sbase + c * 64 + st * 16 + lm] = p;

      float4v cinit;
#pragma unroll
      for (int i = 0; i < 4; ++i)
        cinit[i] = CINIT_COEF * __shfl(p, lq * 4 + i, 64);

      // A fragments: f16 RNE cvt of the same values the old Sh panel held
      // (bitwise-equal MFMA inputs).
      short8 h0, h1;
      h0[0] = (short)f16_bits(x0a.x); h0[1] = (short)f16_bits(x0a.y);
      h0[2] = (short)f16_bits(x0a.z); h0[3] = (short)f16_bits(x0a.w);
      h0[4] = (short)f16_bits(x0b.x); h0[5] = (short)f16_bits(x0b.y);
      h0[6] = (short)f16_bits(x0b.z); h0[7] = (short)f16_bits(x0b.w);
      h1[0] = (short)f16_bits(x1a.x); h1[1] = (short)f16_bits(x1a.y);
      h1[2] = (short)f16_bits(x1a.z); h1[3] = (short)f16_bits(x1a.w);
      h1[4] = (short)f16_bits(x1b.x); h1[5] = (short)f16_bits(x1b.y);
      h1[6] = (short)f16_bits(x1b.z); h1[7] = (short)f16_bits(x1b.w);

#pragma unroll
      for (int t = 0; t < 4; ++t) {
        float4v a = MFMA16F(h0, qh[t][0], cinit);
        a = MFMA16F(h1, qh[t][1], a);
        bmr[t] = fmaxf(fmaxf(fmaxf(a[0], a[1]), a[2]), fmaxf(a[3], bmr[t]));
      }
    }

    if ((((c + 1) * 4) & (BST - 1)) == 0) {  // finished a bmin block
      const int gb = split * (512 / SBLK) + ((c + 1) * 64 / SBLK) - 1;
#pragma unroll
      for (int t = 0; t < 4; ++t) {
        float v = bmr[t];
        v = fmaxf(v, __shfl_xor(v, 16, 64));
        v = fmaxf(v, __shfl_xor(v, 32, 64));
        if (lq == 0) bmin[(size_t)(qbase + t * 16 + lm) * NSB + gb] = -2.0f * v;
        bmr[t] = -FLT_BIG;
      }
    }
    __syncthreads();  // drains stage(c+1) + guards buffer reuse
  }
}

// ---------------------------------------------------------------------------
// K2: phaseB. R21 structure (4 queries/block, work stealing, register-
// staged rescore) but: rescore reads S ROWS directly (identical bytes and
// d-ascending fp32 chains as the S_T path -> identical keys) and sqQ is
// computed locally from sQrow (same fmaf chain as prep -> bitwise equal).
template <int SBLK>
__global__ __launch_bounds__(256, 3) void k_phaseB(
    const float* __restrict__ S,     // [NTOT][64]
    const float* __restrict__ Q,     // [NTOT][64]
    const float* __restrict__ sqS,
    const float* __restrict__ bmin,
    const float* __restrict__ onehot, float* __restrict__ out) {
  constexpr int NSB = NTOT / SBLK;    // 128 or 64
  constexpr int NB64 = NSB / 64;
  constexpr int SPL = SBLK / 64;      // supports per lane: 2 or 4

  __shared__ float sQrow[4][64];
  __shared__ unsigned long long smask[4][NB64];
  __shared__ float sbk[4][4];
  __shared__ int sbi[4][4];

  const int lane = threadIdx.x & 63;
  const int w = threadIdx.x >> 6;
  const int q = blockIdx.x * 4 + w;

  if (lane < 16)
    *(float4*)&sQrow[w][lane * 4] = *(const float4*)&Q[(size_t)q * DIM + lane * 4];

  // sqQ computed locally (d-ascending fmaf == prep's chain, bitwise).
  float sqq = 0.f;
#pragma unroll
  for (int d = 0; d < 64; ++d) {
    const float v = sQrow[w][d];
    sqq = fmaf(v, v, sqq);
  }
  const float eps = EPS_COEF * sqq + EPS_ABS;

  float bv[NB64];
#pragma unroll
  for (int j = 0; j < NB64; ++j) bv[j] = bmin[(size_t)q * NSB + j * 64 + lane];
  float m = bv[0];
#pragma unroll
  for (int j = 1; j < NB64; ++j) m = fminf(m, bv[j]);
#pragma unroll
  for (int d = 1; d < 64; d <<= 1) m = fminf(m, __shfl_xor(m, d, 64));
  const float thr = m + eps;

#pragma unroll
  for (int j = 0; j < NB64; ++j) {
    const unsigned long long msk = __ballot(bv[j] <= thr);
    if (lane == 0) smask[w][j] = msk;
  }
  __syncthreads();  // sQrow + smask visible block-wide

  // Round-robin the combined worklist (ascending block order per query
  // => per-lane ascending support index => strict-< keeps FIRST min).
  int idx = 0;
  for (int qq = 0; qq < 4; ++qq) {
    float bkq = FLT_BIG;
    int biq = 0;
    for (int j = 0; j < NB64; ++j) {
      unsigned long long msk = smask[qq][j];  // uniform broadcast read
      while (msk) {  // wave-uniform control
        const int b = j * 64 + (__ffsll((long long)msk) - 1);
        msk &= msk - 1;
        if ((idx++ & 3) != w) continue;
        const int s0 = b * SBLK + lane * SPL;
        const float* rp = S + (size_t)s0 * 64;
        if (SPL == 2) {
          float a0 = 0.f, a1 = 0.f;
#pragma unroll
          for (int h = 0; h < 2; ++h) {
            float4 x0[8], x1[8];
#pragma unroll
            for (int j2 = 0; j2 < 8; ++j2)
              x0[j2] = *(const float4*)(rp + h * 32 + j2 * 4);
#pragma unroll
            for (int j2 = 0; j2 < 8; ++j2)
              x1[j2] = *(const float4*)(rp + 64 + h * 32 + j2 * 4);
#pragma unroll
            for (int j2 = 0; j2 < 8; ++j2) {
              const int d = h * 32 + j2 * 4;
              a0 = fmaf(sQrow[qq][d + 0], x0[j2].x, a0);
              a1 = fmaf(sQrow[qq][d + 0], x1[j2].x, a1);
              a0 = fmaf(sQrow[qq][d + 1], x0[j2].y, a0);
              a1 = fmaf(sQrow[qq][d + 1], x1[j2].y, a1);
              a0 = fmaf(sQrow[qq][d + 2], x0[j2].z, a0);
              a1 = fmaf(sQrow[qq][d + 2], x1[j2].z, a1);
              a0 = fmaf(sQrow[qq][d + 3], x0[j2].w, a0);
              a1 = fmaf(sQrow[qq][d + 3], x1[j2].w, a1);
            }
          }
          const float2 sq2 = *(const float2*)&sqS[s0];
          const float k0 = fmaf(-2.f, a0, sq2.x);
          const float k1 = fmaf(-2.f, a1, sq2.y);
          bool u;  // ascending index, strict < => first minimum per lane
          u = k0 < bkq; bkq = u ? k0 : bkq; biq = u ? s0 : biq;
          u = k1 < bkq; bkq = u ? k1 : bkq; biq = u ? (s0 + 1) : biq;
        } else {
          float a0 = 0.f, a1 = 0.f, a2 = 0.f, a3 = 0.f;
#pragma unroll
          for (int h = 0; h < 4; ++h) {
            float4 x0[4], x1[4], x2[4], x3[4];
#pragma unroll
            for (int j2 = 0; j2 < 4; ++j2) {
              x0[j2] = *(const float4*)(rp + h * 16 + j2 * 4);
              x1[j2] = *(const float4*)(rp + 64 + h * 16 + j2 * 4);
              x2[j2] = *(const float4*)(rp + 128 + h * 16 + j2 * 4);
              x3[j2] = *(const float4*)(rp + 192 + h * 16 + j2 * 4);
            }
#pragma unroll
            for (int j2 = 0; j2 < 4; ++j2) {
              const int d = h * 16 + j2 * 4;
#pragma unroll
              for (int e = 0; e < 4; ++e) {
                const float qd = sQrow[qq][d + e];
                a0 = fmaf(qd, x0[j2][e], a0);
                a1 = fmaf(qd, x1[j2][e], a1);
                a2 = fmaf(qd, x2[j2][e], a2);
                a3 = fmaf(qd, x3[j2][e], a3);
              }
            }
          }
          const float4 sq4 = *(const float4*)&sqS[s0];
          const float k0 = fmaf(-2.f, a0, sq4.x);
          const float k1 = fmaf(-2.f, a1, sq4.y);
          const float k2 = fmaf(-2.f, a2, sq4.z);
          const float k3 = fmaf(-2.f, a3, sq4.w);
          bool u;
          u = k0 < bkq; bkq = u ? k0 : bkq; biq = u ? s0 : biq;
          u = k1 < bkq; bkq = u ? k1 : bkq; biq = u ? (s0 + 1) : biq;
          u = k2 < bkq; bkq = u ? k2 : bkq; biq = u ? (s0 + 2) : biq;
          u = k3 < bkq; bkq = u ? k3 : bkq; biq = u ? (s0 + 3) : biq;
        }
      }
    }
    // Cross-lane lexicographic argmin on exact keys => first-index.
#pragma unroll
    for (int d = 1; d < 64; d <<= 1) {
      const float ok = __shfl_xor(bkq, d, 64);
      const int oi = __shfl_xor(biq, d, 64);
      const bool u = (ok < bkq) || (ok == bkq && oi < biq);
      bkq = u ? ok : bkq;
      biq = u ? oi : biq;
    }
    if (lane == 0) { sbk[qq][w] = bkq; sbi[qq][w] = biq; }
  }
  __syncthreads();

  // Wave w: lexicographic merge of the 4 wave partials for query w.
  float fk = sbk[w][0];
  int fi = sbi[w][0];
#pragma unroll
  for (int ww = 1; ww < 4; ++ww) {
    const float ok = sbk[w][ww];
    const int oi = sbi[w][ww];
    const bool u = (ok < fk) || (ok == fk && oi < fi);
    fk = u ? ok : fk;
    fi = u ? oi : fi;
  }

  // Label: one-hot rows exact {0,1}; first 1 == np.argmax.
  const float ov = onehot[(size_t)fi * 64 + lane];
  const unsigned long long lmask = __ballot(ov > 0.5f);
  const int label = __ffsll((long long)lmask) - 1;
  out[(size_t)q * 64 + lane] = (lane == label) ? 1.0f : 0.0f;
}

// ---------------------------------------------------------------------------
extern "C" void kernel_launch(void* const* d_in, const int* in_sizes, int n_in,
                              void* d_out, int out_size, void* d_ws, size_t ws_size,
                              hipStream_t stream) {
  const float* S = (const float*)d_in[0];   // [16384][64]
  const float* Q = (const float*)d_in[1];   // [16384][64]
  const float* OH = (const float*)d_in[2];  // [16384][64]
  float* out = (float*)d_out;

  char* ws = (char*)d_ws;
  float* bmin = (float*)ws;  // 8 MB (BST=8) or 4 MB (BST=16)

  if (ws_size >= (9u << 20)) {
    float* sqS = (float*)(ws + (8u << 20));  // 64 KB
    k_phaseA<8><<<dim3(32, NTOT / 256), 256, 0, stream>>>(S, Q, sqS, bmin);
    k_phaseB<128><<<dim3(NTOT / 4), 256, 0, stream>>>(S, Q, sqS, bmin, OH, out);
  } else {
    float* sqS = (float*)(ws + (4u << 20));  // 64 KB
    k_phaseA<16><<<dim3(32, NTOT / 256), 256, 0, stream>>>(S, Q, sqS, bmin);
    k_phaseB<256><<<dim3(NTOT / 4), 256, 0, stream>>>(S, Q, sqS, bmin, OH, out);
  }
  (void)in_sizes; (void)n_in; (void)out_size; (void)ws_size;
}

// Round 8
// 203.871 us; speedup vs baseline: 1.0876x; 1.0876x over previous
//
#include <hip/hip_runtime.h>

// KNN argmin over L2, round 27: 2 dispatches done right.
// K1 = prep+phaseA fused (R25 inner loop verbatim; f32 staged, cvt ONCE
// per chunk, not per step). K2 = R21 phaseB verbatim (S_T coalesced).
//
// R26 post-mortem: K2's S-row reads were stride-512B across lanes (64
// cache lines per load instr) -> 109us; K1 paid per-STEP cvt+shfl (~3x
// R25's step VALU) -> ~110us. Both >> floor, so the ~48.5us/dispatch
// floor theory was not tested. R25's 3x48.6=145.8-exact still stands;
// R26 confirms dur tracks work when work > floor.
//
// K1: grid (32 splits, 64 q-tiles), 256 thr, 4 blocks/CU (LDS 32.5KB).
// Per 64-support chunk: stage 16KB f32 S rows linearly via global_load_lds
// -> sync -> cvt pass (256 thr x 16 elems) builds R8-layout f16 panel +
// ssq[row] = -0.499*|s|^2 (tree order, R26-validated) in LDS; y==0 blocks
// also write S_T (row-major b128 LDS reads, conflict-free; per-dim
// coalesced stores) and raw sqS -> sync -> stage(c+1) overlaps compute:
// R25's exact step loop (ds_read_b128 frags + float4 cinit + 8 MFMA +
// v_max3 fold) -> bmin.
// K2: R21 body (4 q/block, work steal, reg-staged S_T rescore), sqQ local.
//
// Certificate unchanged: c=2^-9*1.01<=0.002, eps=0.004|q|^2+0.05; bmin
// encodes 0.998|s|^2 - 2*cross_f16. Blocks with bmin <= min+eps provably
// contain the true first argmin. |s|^2 tree-order delta absorbed by the
// 0.05 slack (R26: absmax 0).
//
// Ledger: R19 153.3 | R20 steal 153.0 | R21 reg-stage 145.8 | R22 no-op |
// R23 fusion 314.8 (spills) | R24 153.1 | R25 145.8 = 3x48.6 EXACT |
// R26 2-dispatch naive 221.7 (uncoalesced K2, per-step cvt K1).
// Prediction: ~97-108us if floor real; ~145 falsifies floor theory.

#define NTOT   16384
#define DIM    64
#define EPS_COEF 0.004f   // 2c with c=0.002 (>= 2^-9*1.01)
#define EPS_ABS  0.05f
#define CINIT_COEF (-0.499f)  // -(1-c)/2
#define FLT_BIG 3.4e38f

typedef __attribute__((ext_vector_type(8))) short short8;
typedef __attribute__((ext_vector_type(4))) float float4v;

__device__ __forceinline__ ushort f16_bits(float x) {
  union { _Float16 f; ushort u; } c;
  c.f = (_Float16)x;  // v_cvt_f16_f32, RNE
  return c.u;
}

// Opaque def: forbids rematerialization (forces register residency).
__device__ __forceinline__ void pin8(short8& v) {
  asm volatile("" : "+v"(v));
}

#define MFMA16F(A, B, C) __builtin_amdgcn_mfma_f32_16x16x32_f16(A, B, C, 0, 0, 0)

// ---------------------------------------------------------------------------
// K1: fused prep+phaseA. block = 256 queries x 512 supports.
template <int BST>  // 16-support steps per bmin block: 8 -> SBLK=128
__global__ __launch_bounds__(256, 4) void k_phaseA(
    const float* __restrict__ S, const float* __restrict__ Q,
    float* __restrict__ sqS, float* __restrict__ S_T,
    float* __restrict__ bmin) {
  constexpr int NSB = NTOT / (16 * BST);   // 128 or 64
  constexpr int SBLK = 16 * BST;
  __shared__ float fchunk[4096];           // 16KB f32 stage (1 buffer)
  __shared__ ushort spanel[2][4096];       // 2 x 8KB f16 panels (R8 layout)
  __shared__ float ssq[2][64];             // -0.499*|s|^2 per row

  const int tid = threadIdx.x;
  const int l = tid & 63;
  const int w = tid >> 6;
  const int lm = l & 15;
  const int lq = l >> 4;
  const int split = blockIdx.x;            // 0..31
  const int qbase = blockIdx.y * 256 + w * 64;
  const int sbase = split * 512;
  const bool aux = (blockIdx.y == 0);      // S_T + sqS producer

  // Q (B) fragments from raw f32 (R26-verified bitwise == old prep path).
  short8 qh[4][2];
#pragma unroll
  for (int t = 0; t < 4; ++t) {
    const float* qp = Q + (size_t)(qbase + t * 16 + lm) * 64 + lq * 8;
#pragma unroll
    for (int h = 0; h < 2; ++h) {
      const float4 a = *(const float4*)(qp + h * 32);
      const float4 b = *(const float4*)(qp + h * 32 + 4);
      short8 v;
      v[0] = (short)f16_bits(a.x); v[1] = (short)f16_bits(a.y);
      v[2] = (short)f16_bits(a.z); v[3] = (short)f16_bits(a.w);
      v[4] = (short)f16_bits(b.x); v[5] = (short)f16_bits(b.y);
      v[6] = (short)f16_bits(b.z); v[7] = (short)f16_bits(b.w);
      qh[t][h] = v;
    }
  }
#pragma unroll
  for (int t = 0; t < 4; ++t) { pin8(qh[t][0]); pin8(qh[t][1]); }

  // Linear 16KB copy: chunk c = 64 contiguous S rows (f32). Wave w stages
  // its 4KB quarter with 4 issues (wave-uniform LDS base, per-lane src).
  auto stage = [&](int c) {
    const float* gs = S + (size_t)(sbase + c * 64) * 64;
#pragma unroll
    for (int I = 0; I < 4; ++I) {
      const float* src = gs + w * 1024 + I * 256 + l * 4;
      float* dst = &fchunk[w * 1024 + I * 256];
      __builtin_amdgcn_global_load_lds(
          (const __attribute__((address_space(1))) void*)(const void*)src,
          (__attribute__((address_space(3))) void*)(void*)dst, 16, 0, 0);
    }
  };

  float bmr[4] = {-FLT_BIG, -FLT_BIG, -FLT_BIG, -FLT_BIG};

  stage(0);
  __syncthreads();  // compiler drains vmcnt before barrier: chunk0 resident

  for (int c = 0; c < 8; ++c) {
    const int pb = c & 1;

    // --- cvt pass: f32 chunk -> f16 panel (R8 layout), once per element.
    // thread covers 2 groups of 8 dims: G = tid*2+gi; r=G>>3, g=G&7.
#pragma unroll
    for (int gi = 0; gi < 2; ++gi) {
      const int G = tid * 2 + gi;
      const int r = G >> 3;
      const int g = G & 7;
      const int half = g >> 2;
      const int q8 = g & 3;
      const float4 a = *(const float4*)&fchunk[r * 64 + g * 8];
      const float4 b = *(const float4*)&fchunk[r * 64 + g * 8 + 4];
      short8 v;
      v[0] = (short)f16_bits(a.x); v[1] = (short)f16_bits(a.y);
      v[2] = (short)f16_bits(a.z); v[3] = (short)f16_bits(a.w);
      v[4] = (short)f16_bits(b.x); v[5] = (short)f16_bits(b.y);
      v[6] = (short)f16_bits(b.z); v[7] = (short)f16_bits(b.w);
      *(short8*)&spanel[pb][(r >> 4) * 1024 + half * 512 +
                            (q8 * 16 + (r & 15)) * 8] = v;
    }

    // --- |s|^2 pass: wave w rows w*16+lm; lane part lq covers 16 dims;
    // butterfly over lq (tree order, certified by 0.05 slack; R26 abs=0).
    {
      const int row = w * 16 + lm;
      const float* rp = &fchunk[row * 64 + lq * 16];
      float p = 0.f;
#pragma unroll
      for (int j = 0; j < 4; ++j) {
        const float4 x = *(const float4*)(rp + j * 4);
        p = fmaf(x.x, x.x, p); p = fmaf(x.y, x.y, p);
        p = fmaf(x.z, x.z, p); p = fmaf(x.w, x.w, p);
      }
      p += __shfl_xor(p, 16, 64);
      p += __shfl_xor(p, 32, 64);
      if (lq == 0) {
        ssq[pb][row] = CINIT_COEF * p;
        if (aux) sqS[sbase + c * 64 + row] = p;
      }
    }

    // --- S_T pass (aux blocks): conflict-free row-major b128 LDS reads,
    // per-dim coalesced stores (lane l -> support sbase+c*64+l).
    if (aux) {
      const int sb = sbase + c * 64;
#pragma unroll
      for (int k = 0; k < 4; ++k) {
        const int d0 = w * 16 + k * 4;
        const float4 x = *(const float4*)&fchunk[l * 64 + d0];
        S_T[(size_t)(d0 + 0) * NTOT + sb + l] = x.x;
        S_T[(size_t)(d0 + 1) * NTOT + sb + l] = x.y;
        S_T[(size_t)(d0 + 2) * NTOT + sb + l] = x.z;
        S_T[(size_t)(d0 + 3) * NTOT + sb + l] = x.w;
      }
    }

    __syncthreads();              // panel[pb]/ssq[pb] ready; fchunk free
    if (c + 1 < 8) stage(c + 1);  // async refill overlaps compute

    // --- compute: R25 step loop verbatim (frags from f16 panel).
#pragma unroll
    for (int st = 0; st < 4; ++st) {
      const short8 h0 = *(const short8*)&spanel[pb][st * 1024 + l * 8];
      const short8 h1 = *(const short8*)&spanel[pb][st * 1024 + 512 + l * 8];
      const float4 sqv = *(const float4*)&ssq[pb][st * 16 + lq * 4];
      float4v cinit;
      cinit[0] = sqv.x; cinit[1] = sqv.y;
      cinit[2] = sqv.z; cinit[3] = sqv.w;
#pragma unroll
      for (int t = 0; t < 4; ++t) {
        float4v a = MFMA16F(h0, qh[t][0], cinit);
        a = MFMA16F(h1, qh[t][1], a);
        bmr[t] = fmaxf(fmaxf(fmaxf(a[0], a[1]), a[2]), fmaxf(a[3], bmr[t]));
      }
    }

    if ((((c + 1) * 4) & (BST - 1)) == 0) {  // finished a bmin block
      const int gb = split * (512 / SBLK) + ((c + 1) * 64 / SBLK) - 1;
#pragma unroll
      for (int t = 0; t < 4; ++t) {
        float v = bmr[t];
        v = fmaxf(v, __shfl_xor(v, 16, 64));
        v = fmaxf(v, __shfl_xor(v, 32, 64));
        if (lq == 0) bmin[(size_t)(qbase + t * 16 + lm) * NSB + gb] = -2.0f * v;
        bmr[t] = -FLT_BIG;
      }
    }
    __syncthreads();  // drains stage(c+1); guards panel/ssq/fchunk reuse
  }
}

// ---------------------------------------------------------------------------
// K2: phaseB, R21 body verbatim (S_T coalesced rescore; best measured
// 48.7us) with sqQ computed locally (R26-verified bitwise).
template <int SBLK>
__global__ __launch_bounds__(256, 3) void k_phaseB(
    const float* __restrict__ S_T,   // [64][NTOT]
    const float* __restrict__ Q,     // [NTOT][64]
    const float* __restrict__ sqS,
    const float* __restrict__ bmin,
    const float* __restrict__ onehot, float* __restrict__ out) {
  constexpr int NSB = NTOT / SBLK;    // 128 or 64
  constexpr int NB64 = NSB / 64;
  constexpr int SPL = SBLK / 64;      // supports per lane: 2 or 4

  __shared__ float sQrow[4][64];
  __shared__ unsigned long long smask[4][NB64];
  __shared__ float sbk[4][4];
  __shared__ int sbi[4][4];

  const int lane = threadIdx.x & 63;
  const int w = threadIdx.x >> 6;
  const int q = blockIdx.x * 4 + w;

  if (lane < 16)
    *(float4*)&sQrow[w][lane * 4] = *(const float4*)&Q[(size_t)q * DIM + lane * 4];

  // sqQ locally (d-ascending fmaf chain == old prep, bitwise).
  float sqq = 0.f;
#pragma unroll
  for (int d = 0; d < 64; ++d) {
    const float v = sQrow[w][d];
    sqq = fmaf(v, v, sqq);
  }
  const float eps = EPS_COEF * sqq + EPS_ABS;

  float bv[NB64];
#pragma unroll
  for (int j = 0; j < NB64; ++j) bv[j] = bmin[(size_t)q * NSB + j * 64 + lane];
  float m = bv[0];
#pragma unroll
  for (int j = 1; j < NB64; ++j) m = fminf(m, bv[j]);
#pragma unroll
  for (int d = 1; d < 64; d <<= 1) m = fminf(m, __shfl_xor(m, d, 64));
  const float thr = m + eps;

#pragma unroll
  for (int j = 0; j < NB64; ++j) {
    const unsigned long long msk = __ballot(bv[j] <= thr);
    if (lane == 0) smask[w][j] = msk;
  }
  __syncthreads();  // sQrow + smask visible block-wide

  // Round-robin combined worklist (ascending block order per query =>
  // per-lane ascending support index => strict-< keeps FIRST min).
  int idx = 0;
  for (int qq = 0; qq < 4; ++qq) {
    float bkq = FLT_BIG;
    int biq = 0;
    for (int j = 0; j < NB64; ++j) {
      unsigned long long msk = smask[qq][j];  // uniform broadcast read
      while (msk) {  // wave-uniform control
        const int b = j * 64 + (__ffsll((long long)msk) - 1);
        msk &= msk - 1;
        if ((idx++ & 3) != w) continue;
        const int s0 = b * SBLK + lane * SPL;
        if (SPL == 2) {
          float a0 = 0.f, a1 = 0.f;
#pragma unroll
          for (int h = 0; h < 2; ++h) {
            float2 x[32];
#pragma unroll
            for (int d = 0; d < 32; ++d)
              x[d] = *(const float2*)&S_T[(size_t)(h * 32 + d) * NTOT + s0];
#pragma unroll
            for (int d = 0; d < 32; ++d) {
              const float qd = sQrow[qq][h * 32 + d];
              a0 = fmaf(qd, x[d].x, a0);
              a1 = fmaf(qd, x[d].y, a1);
            }
          }
          const float2 sq2 = *(const float2*)&sqS[s0];
          const float k0 = fmaf(-2.f, a0, sq2.x);
          const float k1 = fmaf(-2.f, a1, sq2.y);
          bool u;  // ascending index, strict < => first minimum per lane
          u = k0 < bkq; bkq = u ? k0 : bkq; biq = u ? s0 : biq;
          u = k1 < bkq; bkq = u ? k1 : bkq; biq = u ? (s0 + 1) : biq;
        } else {
          float a0 = 0.f, a1 = 0.f, a2 = 0.f, a3 = 0.f;
#pragma unroll
          for (int hh = 0; hh < 4; ++hh) {
            float4 x[16];
#pragma unroll
            for (int d = 0; d < 16; ++d)
              x[d] = *(const float4*)&S_T[(size_t)(hh * 16 + d) * NTOT + s0];
#pragma unroll
            for (int d = 0; d < 16; ++d) {
              const float qd = sQrow[qq][hh * 16 + d];
              a0 = fmaf(qd, x[d].x, a0);
              a1 = fmaf(qd, x[d].y, a1);
              a2 = fmaf(qd, x[d].z, a2);
              a3 = fmaf(qd, x[d].w, a3);
            }
          }
          const float4 sq4 = *(const float4*)&sqS[s0];
          const float k0 = fmaf(-2.f, a0, sq4.x);
          const float k1 = fmaf(-2.f, a1, sq4.y);
          const float k2 = fmaf(-2.f, a2, sq4.z);
          const float k3 = fmaf(-2.f, a3, sq4.w);
          bool u;
          u = k0 < bkq; bkq = u ? k0 : bkq; biq = u ? s0 : biq;
          u = k1 < bkq; bkq = u ? k1 : bkq; biq = u ? (s0 + 1) : biq;
          u = k2 < bkq; bkq = u ? k2 : bkq; biq = u ? (s0 + 2) : biq;
          u = k3 < bkq; bkq = u ? k3 : bkq; biq = u ? (s0 + 3) : biq;
        }
      }
    }
    // Cross-lane lexicographic argmin on exact keys => first-index.
#pragma unroll
    for (int d = 1; d < 64; d <<= 1) {
      const float ok = __shfl_xor(bkq, d, 64);
      const int oi = __shfl_xor(biq, d, 64);
      const bool u = (ok < bkq) || (ok == bkq && oi < biq);
      bkq = u ? ok : bkq;
      biq = u ? oi : biq;
    }
    if (lane == 0) { sbk[qq][w] = bkq; sbi[qq][w] = biq; }
  }
  __syncthreads();

  // Wave w: lexicographic merge of the 4 wave partials for query w.
  float fk = sbk[w][0];
  int fi = sbi[w][0];
#pragma unroll
  for (int ww = 1; ww < 4; ++ww) {
    const float ok = sbk[w][ww];
    const int oi = sbi[w][ww];
    const bool u = (ok < fk) || (ok == fk && oi < fi);
    fk = u ? ok : fk;
    fi = u ? oi : fi;
  }

  // Label: one-hot rows exact {0,1}; first 1 == np.argmax.
  const float ov = onehot[(size_t)fi * 64 + lane];
  const unsigned long long lmask = __ballot(ov > 0.5f);
  const int label = __ffsll((long long)lmask) - 1;
  out[(size_t)q * 64 + lane] = (lane == label) ? 1.0f : 0.0f;
}

// ---------------------------------------------------------------------------
extern "C" void kernel_launch(void* const* d_in, const int* in_sizes, int n_in,
                              void* d_out, int out_size, void* d_ws, size_t ws_size,
                              hipStream_t stream) {
  const float* S = (const float*)d_in[0];   // [16384][64]
  const float* Q = (const float*)d_in[1];   // [16384][64]
  const float* OH = (const float*)d_in[2];  // [16384][64]
  float* out = (float*)d_out;

  char* ws = (char*)d_ws;
  float* S_T = (float*)ws;                         // [0, 4MB)
  float* sqS = (float*)(ws + (4u << 20));          // 64 KB
  float* bmin = (float*)(ws + (4u << 20) + (64u << 10));  // 8 or 4 MB

  if (ws_size >= (13u << 20)) {
    k_phaseA<8><<<dim3(32, NTOT / 256), 256, 0, stream>>>(S, Q, sqS, S_T, bmin);
    k_phaseB<128><<<dim3(NTOT / 4), 256, 0, stream>>>(S_T, Q, sqS, bmin, OH, out);
  } else {
    k_phaseA<16><<<dim3(32, NTOT / 256), 256, 0, stream>>>(S, Q, sqS, S_T, bmin);
    k_phaseB<256><<<dim3(NTOT / 4), 256, 0, stream>>>(S_T, Q, sqS, bmin, OH, out);
  }
  (void)in_sizes; (void)n_in; (void)out_size; (void)ws_size;
}

// Round 9
// 160.711 us; speedup vs baseline: 1.3797x; 1.2686x over previous
//
#include <hip/hip_runtime.h>

// KNN argmin over L2, round 28: 2 dispatches, register-staged K1 (no f32
// LDS round-trip -> no bank conflicts).
//
// R27 post-mortem: SQ_LDS_BANK_CONFLICT 3.79e7 (vs 0 all prior rounds).
// fchunk reads at row-stride 64 floats (= 0 mod 32 banks) made cvt pass,
// |s|^2 pass, and S_T transpose each 16-way conflicted inside barriers.
// MfmaUtil 12 / VALU 17 / HBM 10: nothing else near a limit.
//
// R28 K1: thread l of wave w loads 16 floats of row w*16+(l&15), dims
// (l>>4)*8 +{0..7} and 32+(l>>4)*8+{0..7} (4x float4, coalesced). From
// registers: (1) f16 cvt -> R8 panel; write offsets reduce to w*2048+l*16
// (+1024) = lane-contiguous ds_write_b128, conflict-free by construction;
// (2) |s|^2 partial in-reg + shfl_xor(16/32) tree reduce (certificate
// slack covers order; R26 absmax 0); (3) aux (y==0) blocks store S_T
// straight from registers (64B-coalesced per 16-lane group). fchunk
// deleted (LDS 33->17KB). One barrier/chunk; next-chunk loads issued
// before the barrier so HBM latency hides under MFMA (T14). Compute pass
// = R25/R27 verbatim (conflict-free, bitwise-identical panel bytes).
// K2 = R21 phaseB verbatim (proven 48.5-49us).
//
// Certificate unchanged: c=2^-9*1.01<=0.002, eps=0.004|q|^2+0.05; bmin
// encodes 0.998|s|^2 - 2*cross_f16 via cinit=-0.499|s|^2. Blocks with
// bmin <= min+eps provably contain the true first argmin.
//
// Ledger: R19 153.3 | R20 steal 153.0 | R21 reg-stage 145.8 | R22 no-op |
// R23 coop fusion 314.8 (spills) | R24 153.1 | R25 145.8 = 3x48.6 EXACT |
// R26 221.7 (uncoalesced K2 rows) | R27 203.9 (K1 16-way LDS conflicts).
// Floor theory: ~48.5us/dispatch minimum. Prediction: phaseA conflicts
// ->~0, dur ->~48-52; total ~97-105. phaseA >80 with 0 conflicts would
// falsify the conflict diagnosis; total ~145 falsifies the floor theory.

#define NTOT   16384
#define DIM    64
#define EPS_COEF 0.004f   // 2c with c=0.002 (>= 2^-9*1.01)
#define EPS_ABS  0.05f
#define CINIT_COEF (-0.499f)  // -(1-c)/2
#define FLT_BIG 3.4e38f

typedef __attribute__((ext_vector_type(8))) short short8;
typedef __attribute__((ext_vector_type(4))) float float4v;

__device__ __forceinline__ ushort f16_bits(float x) {
  union { _Float16 f; ushort u; } c;
  c.f = (_Float16)x;  // v_cvt_f16_f32, RNE
  return c.u;
}

// Opaque def: forbids rematerialization (forces register residency).
__device__ __forceinline__ void pin8(short8& v) {
  asm volatile("" : "+v"(v));
}

#define MFMA16F(A, B, C) __builtin_amdgcn_mfma_f32_16x16x32_f16(A, B, C, 0, 0, 0)

// ---------------------------------------------------------------------------
// K1: fused prep+phaseA, register-staged. block = 256 queries x 512
// supports; grid (32 splits, 64 q-tiles); split slice XCD-local (x%8).
template <int BST>  // 16-support steps per bmin block: 8 -> SBLK=128
__global__ __launch_bounds__(256, 3) void k_phaseA(
    const float* __restrict__ S, const float* __restrict__ Q,
    float* __restrict__ sqS, float* __restrict__ S_T,
    float* __restrict__ bmin) {
  constexpr int NSB = NTOT / (16 * BST);   // 128 or 64
  constexpr int SBLK = 16 * BST;
  __shared__ ushort spanel[2][4096];       // 2 x 8KB f16 panels (R8 layout)
  __shared__ float ssq[2][64];             // -0.499*|s|^2 per chunk row

  const int tid = threadIdx.x;
  const int l = tid & 63;
  const int w = tid >> 6;
  const int lm = l & 15;
  const int lq = l >> 4;                   // doubles as q8 (dim group)
  const int split = blockIdx.x;            // 0..31
  const int qbase = blockIdx.y * 256 + w * 64;
  const int sbase = split * 512;
  const bool aux = (blockIdx.y == 0);      // S_T + sqS producer

  // Q (B) fragments from raw f32 (R26/R27-verified bitwise == prep path).
  short8 qh[4][2];
#pragma unroll
  for (int t = 0; t < 4; ++t) {
    const float* qp = Q + (size_t)(qbase + t * 16 + lm) * 64 + lq * 8;
#pragma unroll
    for (int h = 0; h < 2; ++h) {
      const float4 a = *(const float4*)(qp + h * 32);
      const float4 b = *(const float4*)(qp + h * 32 + 4);
      short8 v;
      v[0] = (short)f16_bits(a.x); v[1] = (short)f16_bits(a.y);
      v[2] = (short)f16_bits(a.z); v[3] = (short)f16_bits(a.w);
      v[4] = (short)f16_bits(b.x); v[5] = (short)f16_bits(b.y);
      v[6] = (short)f16_bits(b.z); v[7] = (short)f16_bits(b.w);
      qh[t][h] = v;
    }
  }
#pragma unroll
  for (int t = 0; t < 4; ++t) { pin8(qh[t][0]); pin8(qh[t][1]); }

  // Per-thread staging address: row w*16+lm of the chunk, dims lq*8 base.
  const float* rp0 = S + (size_t)(sbase + w * 16 + lm) * 64 + lq * 8;

  float4 xa0, xa1, xa2, xa3, xb0, xb1, xb2, xb3;
  {
    const float* rp = rp0;  // chunk 0
    xa0 = *(const float4*)(rp);
    xa1 = *(const float4*)(rp + 4);
    xa2 = *(const float4*)(rp + 32);
    xa3 = *(const float4*)(rp + 36);
  }

  float bmr[4] = {-FLT_BIG, -FLT_BIG, -FLT_BIG, -FLT_BIG};

  for (int c = 0; c < 8; ++c) {
    const int pb = c & 1;

    // --- cvt from registers -> R8 panel. Offsets are w*2048 + l*16 bytes
    // (+1024): lane-contiguous b128 writes, conflict-free by construction.
    {
      short8 v0, v1;
      v0[0] = (short)f16_bits(xa0.x); v0[1] = (short)f16_bits(xa0.y);
      v0[2] = (short)f16_bits(xa0.z); v0[3] = (short)f16_bits(xa0.w);
      v0[4] = (short)f16_bits(xa1.x); v0[5] = (short)f16_bits(xa1.y);
      v0[6] = (short)f16_bits(xa1.z); v0[7] = (short)f16_bits(xa1.w);
      v1[0] = (short)f16_bits(xa2.x); v1[1] = (short)f16_bits(xa2.y);
      v1[2] = (short)f16_bits(xa2.z); v1[3] = (short)f16_bits(xa2.w);
      v1[4] = (short)f16_bits(xa3.x); v1[5] = (short)f16_bits(xa3.y);
      v1[6] = (short)f16_bits(xa3.z); v1[7] = (short)f16_bits(xa3.w);
      *(short8*)&spanel[pb][w * 1024 + l * 8] = v0;        // half 0
      *(short8*)&spanel[pb][w * 1024 + 512 + l * 8] = v1;  // half 1
    }

    // --- |s|^2 from registers: 16-dim partial + shfl_xor tree (16, 32).
    {
      float p = 0.f;
      p = fmaf(xa0.x, xa0.x, p); p = fmaf(xa0.y, xa0.y, p);
      p = fmaf(xa0.z, xa0.z, p); p = fmaf(xa0.w, xa0.w, p);
      p = fmaf(xa1.x, xa1.x, p); p = fmaf(xa1.y, xa1.y, p);
      p = fmaf(xa1.z, xa1.z, p); p = fmaf(xa1.w, xa1.w, p);
      p = fmaf(xa2.x, xa2.x, p); p = fmaf(xa2.y, xa2.y, p);
      p = fmaf(xa2.z, xa2.z, p); p = fmaf(xa2.w, xa2.w, p);
      p = fmaf(xa3.x, xa3.x, p); p = fmaf(xa3.y, xa3.y, p);
      p = fmaf(xa3.z, xa3.z, p); p = fmaf(xa3.w, xa3.w, p);
      p += __shfl_xor(p, 16, 64);
      p += __shfl_xor(p, 32, 64);
      if (lq == 0) {
        ssq[pb][w * 16 + lm] = CINIT_COEF * p;
        if (aux) sqS[sbase + c * 64 + w * 16 + lm] = p;
      }
    }

    // --- S_T straight from registers (aux blocks only): per-d scalar
    // stores; 16 lanes sharing lq write 16 consecutive floats (64B).
    if (aux) {
      const int srow = sbase + c * 64 + w * 16 + lm;
      const int d0 = lq * 8;
      S_T[(size_t)(d0 + 0) * NTOT + srow] = xa0.x;
      S_T[(size_t)(d0 + 1) * NTOT + srow] = xa0.y;
      S_T[(size_t)(d0 + 2) * NTOT + srow] = xa0.z;
      S_T[(size_t)(d0 + 3) * NTOT + srow] = xa0.w;
      S_T[(size_t)(d0 + 4) * NTOT + srow] = xa1.x;
      S_T[(size_t)(d0 + 5) * NTOT + srow] = xa1.y;
      S_T[(size_t)(d0 + 6) * NTOT + srow] = xa1.z;
      S_T[(size_t)(d0 + 7) * NTOT + srow] = xa1.w;
      S_T[(size_t)(32 + d0 + 0) * NTOT + srow] = xa2.x;
      S_T[(size_t)(32 + d0 + 1) * NTOT + srow] = xa2.y;
      S_T[(size_t)(32 + d0 + 2) * NTOT + srow] = xa2.z;
      S_T[(size_t)(32 + d0 + 3) * NTOT + srow] = xa2.w;
      S_T[(size_t)(32 + d0 + 4) * NTOT + srow] = xa3.x;
      S_T[(size_t)(32 + d0 + 5) * NTOT + srow] = xa3.y;
      S_T[(size_t)(32 + d0 + 6) * NTOT + srow] = xa3.z;
      S_T[(size_t)(32 + d0 + 7) * NTOT + srow] = xa3.w;
    }

    // --- prefetch next chunk into regs; latency hides under the barrier
    // + MFMA phase (T14 issue-early / use-late).
    if (c + 1 < 8) {
      const float* rp = rp0 + (size_t)(c + 1) * 64 * 64;
      xb0 = *(const float4*)(rp);
      xb1 = *(const float4*)(rp + 4);
      xb2 = *(const float4*)(rp + 32);
      xb3 = *(const float4*)(rp + 36);
    }

    __syncthreads();  // panel[pb]/ssq[pb] ready (cross-wave)

    // --- compute: R25/R27 step loop verbatim (conflict-free b128 reads).
#pragma unroll
    for (int st = 0; st < 4; ++st) {
      const short8 h0 = *(const short8*)&spanel[pb][st * 1024 + l * 8];
      const short8 h1 = *(const short8*)&spanel[pb][st * 1024 + 512 + l * 8];
      const float4 sqv = *(const float4*)&ssq[pb][st * 16 + lq * 4];
      float4v cinit;
      cinit[0] = sqv.x; cinit[1] = sqv.y;
      cinit[2] = sqv.z; cinit[3] = sqv.w;
#pragma unroll
      for (int t = 0; t < 4; ++t) {
        float4v a = MFMA16F(h0, qh[t][0], cinit);
        a = MFMA16F(h1, qh[t][1], a);
        bmr[t] = fmaxf(fmaxf(fmaxf(a[0], a[1]), a[2]), fmaxf(a[3], bmr[t]));
      }
    }

    if ((((c + 1) * 4) & (BST - 1)) == 0) {  // finished a bmin block
      const int gb = split * (512 / SBLK) + ((c + 1) * 64 / SBLK) - 1;
#pragma unroll
      for (int t = 0; t < 4; ++t) {
        float v = bmr[t];
        v = fmaxf(v, __shfl_xor(v, 16, 64));
        v = fmaxf(v, __shfl_xor(v, 32, 64));
        if (lq == 0) bmin[(size_t)(qbase + t * 16 + lm) * NSB + gb] = -2.0f * v;
        bmr[t] = -FLT_BIG;
      }
    }

    if (c + 1 < 8) { xa0 = xb0; xa1 = xb1; xa2 = xb2; xa3 = xb3; }
    // No second barrier needed: next PROCESS writes buffer pb^1, which no
    // wave can still be reading (compute(c-1) finished before barrier(c)).
  }
}

// ---------------------------------------------------------------------------
// K2: phaseB, R21 body verbatim (S_T coalesced rescore; proven 48.5-49us)
// with sqQ computed locally (R26-verified bitwise).
template <int SBLK>
__global__ __launch_bounds__(256, 3) void k_phaseB(
    const float* __restrict__ S_T,   // [64][NTOT]
    const float* __restrict__ Q,     // [NTOT][64]
    const float* __restrict__ sqS,
    const float* __restrict__ bmin,
    const float* __restrict__ onehot, float* __restrict__ out) {
  constexpr int NSB = NTOT / SBLK;    // 128 or 64
  constexpr int NB64 = NSB / 64;
  constexpr int SPL = SBLK / 64;      // supports per lane: 2 or 4

  __shared__ float sQrow[4][64];
  __shared__ unsigned long long smask[4][NB64];
  __shared__ float sbk[4][4];
  __shared__ int sbi[4][4];

  const int lane = threadIdx.x & 63;
  const int w = threadIdx.x >> 6;
  const int q = blockIdx.x * 4 + w;

  if (lane < 16)
    *(float4*)&sQrow[w][lane * 4] = *(const float4*)&Q[(size_t)q * DIM + lane * 4];

  // sqQ locally (d-ascending fmaf chain == old prep, bitwise).
  float sqq = 0.f;
#pragma unroll
  for (int d = 0; d < 64; ++d) {
    const float v = sQrow[w][d];
    sqq = fmaf(v, v, sqq);
  }
  const float eps = EPS_COEF * sqq + EPS_ABS;

  float bv[NB64];
#pragma unroll
  for (int j = 0; j < NB64; ++j) bv[j] = bmin[(size_t)q * NSB + j * 64 + lane];
  float m = bv[0];
#pragma unroll
  for (int j = 1; j < NB64; ++j) m = fminf(m, bv[j]);
#pragma unroll
  for (int d = 1; d < 64; d <<= 1) m = fminf(m, __shfl_xor(m, d, 64));
  const float thr = m + eps;

#pragma unroll
  for (int j = 0; j < NB64; ++j) {
    const unsigned long long msk = __ballot(bv[j] <= thr);
    if (lane == 0) smask[w][j] = msk;
  }
  __syncthreads();  // sQrow + smask visible block-wide

  // Round-robin combined worklist (ascending block order per query =>
  // per-lane ascending support index => strict-< keeps FIRST min).
  int idx = 0;
  for (int qq = 0; qq < 4; ++qq) {
    float bkq = FLT_BIG;
    int biq = 0;
    for (int j = 0; j < NB64; ++j) {
      unsigned long long msk = smask[qq][j];  // uniform broadcast read
      while (msk) {  // wave-uniform control
        const int b = j * 64 + (__ffsll((long long)msk) - 1);
        msk &= msk - 1;
        if ((idx++ & 3) != w) continue;
        const int s0 = b * SBLK + lane * SPL;
        if (SPL == 2) {
          float a0 = 0.f, a1 = 0.f;
#pragma unroll
          for (int h = 0; h < 2; ++h) {
            float2 x[32];
#pragma unroll
            for (int d = 0; d < 32; ++d)
              x[d] = *(const float2*)&S_T[(size_t)(h * 32 + d) * NTOT + s0];
#pragma unroll
            for (int d = 0; d < 32; ++d) {
              const float qd = sQrow[qq][h * 32 + d];
              a0 = fmaf(qd, x[d].x, a0);
              a1 = fmaf(qd, x[d].y, a1);
            }
          }
          const float2 sq2 = *(const float2*)&sqS[s0];
          const float k0 = fmaf(-2.f, a0, sq2.x);
          const float k1 = fmaf(-2.f, a1, sq2.y);
          bool u;  // ascending index, strict < => first minimum per lane
          u = k0 < bkq; bkq = u ? k0 : bkq; biq = u ? s0 : biq;
          u = k1 < bkq; bkq = u ? k1 : bkq; biq = u ? (s0 + 1) : biq;
        } else {
          float a0 = 0.f, a1 = 0.f, a2 = 0.f, a3 = 0.f;
#pragma unroll
          for (int hh = 0; hh < 4; ++hh) {
            float4 x[16];
#pragma unroll
            for (int d = 0; d < 16; ++d)
              x[d] = *(const float4*)&S_T[(size_t)(hh * 16 + d) * NTOT + s0];
#pragma unroll
            for (int d = 0; d < 16; ++d) {
              const float qd = sQrow[qq][hh * 16 + d];
              a0 = fmaf(qd, x[d].x, a0);
              a1 = fmaf(qd, x[d].y, a1);
              a2 = fmaf(qd, x[d].z, a2);
              a3 = fmaf(qd, x[d].w, a3);
            }
          }
          const float4 sq4 = *(const float4*)&sqS[s0];
          const float k0 = fmaf(-2.f, a0, sq4.x);
          const float k1 = fmaf(-2.f, a1, sq4.y);
          const float k2 = fmaf(-2.f, a2, sq4.z);
          const float k3 = fmaf(-2.f, a3, sq4.w);
          bool u;
          u = k0 < bkq; bkq = u ? k0 : bkq; biq = u ? s0 : biq;
          u = k1 < bkq; bkq = u ? k1 : bkq; biq = u ? (s0 + 1) : biq;
          u = k2 < bkq; bkq = u ? k2 : bkq; biq = u ? (s0 + 2) : biq;
          u = k3 < bkq; bkq = u ? k3 : bkq; biq = u ? (s0 + 3) : biq;
        }
      }
    }
    // Cross-lane lexicographic argmin on exact keys => first-index.
#pragma unroll
    for (int d = 1; d < 64; d <<= 1) {
      const float ok = __shfl_xor(bkq, d, 64);
      const int oi = __shfl_xor(biq, d, 64);
      const bool u = (ok < bkq) || (ok == bkq && oi < biq);
      bkq = u ? ok : bkq;
      biq = u ? oi : biq;
    }
    if (lane == 0) { sbk[qq][w] = bkq; sbi[qq][w] = biq; }
  }
  __syncthreads();

  // Wave w: lexicographic merge of the 4 wave partials for query w.
  float fk = sbk[w][0];
  int fi = sbi[w][0];
#pragma unroll
  for (int ww = 1; ww < 4; ++ww) {
    const float ok = sbk[w][ww];
    const int oi = sbi[w][ww];
    const bool u = (ok < fk) || (ok == fk && oi < fi);
    fk = u ? ok : fk;
    fi = u ? oi : fi;
  }

  // Label: one-hot rows exact {0,1}; first 1 == np.argmax.
  const float ov = onehot[(size_t)fi * 64 + lane];
  const unsigned long long lmask = __ballot(ov > 0.5f);
  const int label = __ffsll((long long)lmask) - 1;
  out[(size_t)q * 64 + lane] = (lane == label) ? 1.0f : 0.0f;
}

// ---------------------------------------------------------------------------
extern "C" void kernel_launch(void* const* d_in, const int* in_sizes, int n_in,
                              void* d_out, int out_size, void* d_ws, size_t ws_size,
                              hipStream_t stream) {
  const float* S = (const float*)d_in[0];   // [16384][64]
  const float* Q = (const float*)d_in[1];   // [16384][64]
  const float* OH = (const float*)d_in[2];  // [16384][64]
  float* out = (float*)d_out;

  char* ws = (char*)d_ws;
  float* S_T = (float*)ws;                         // [0, 4MB)
  float* sqS = (float*)(ws + (4u << 20));          // 64 KB
  float* bmin = (float*)(ws + (4u << 20) + (64u << 10));  // 8 or 4 MB

  if (ws_size >= (13u << 20)) {
    k_phaseA<8><<<dim3(32, NTOT / 256), 256, 0, stream>>>(S, Q, sqS, S_T, bmin);
    k_phaseB<128><<<dim3(NTOT / 4), 256, 0, stream>>>(S_T, Q, sqS, bmin, OH, out);
  } else {
    k_phaseA<16><<<dim3(32, NTOT / 256), 256, 0, stream>>>(S, Q, sqS, S_T, bmin);
    k_phaseB<256><<<dim3(NTOT / 4), 256, 0, stream>>>(S_T, Q, sqS, bmin, OH, out);
  }
  (void)in_sizes; (void)n_in; (void)out_size; (void)ws_size;
}